// Round 16
// baseline (260.248 us; speedup 1.0000x reference)
//
#include <hip/hip_runtime.h>

#define B_ 1024
#define S_ 256
#define D_ 128
#define K_ 26
#define EST 28   // e_lds row stride in floats (112 B, 16B-aligned rows)

typedef float v2f __attribute__((ext_vector_type(2)));
#define EMAX(a, b) __builtin_elementwise_max((a), (b))

// 4-wave fused CRF, phase-separated to keep the serial chain's LDS pipe clean:
//   wave1: producer (emissions -> e_lds rows, r14-proven bits), then sleeps.
//   wave0: consumer — minimal delta-only recurrence; delta_t OVERWRITES e_lds
//          row t (publish & history unify; gather reads row t-1).
//   after serial-done: ALL 4 waves recompute bp[t] in parallel (t mod 4),
//          bit-identical operands -> identical first-argmax (r15-validated).
//   wave0: r12-proven fence-only backtrack, coalesced store.
__global__ __launch_bounds__(256) void crf_ph(
    const float* __restrict__ X, const float* __restrict__ W,
    const float* __restrict__ Tr, int* __restrict__ out)
{
  __shared__ __align__(16) float e_lds[S_ * EST];   // 28672 B (e, then delta history)
  __shared__ __align__(16) float ring[2][D_];       //  1024 B producer dbuf
  __shared__ unsigned char bp[K_][260];             //  6760 B
  __shared__ int prog[8];                           //    32 B  (~36.5 KB)

  const int tid  = threadIdx.x;
  const int lane = tid & 63;
  const int wv   = tid >> 6;     // 0 consumer, 1 producer, 2/3 bp helpers
  const int b    = blockIdx.x;
  const int jc   = (lane < K_) ? lane : (K_ - 1);

  if (tid < 8) prog[tid] = 0;
  __syncthreads();                                  // only all-wave barrier

  // every wave preloads its transition column (global reads; off the LDS pipe)
  float tc[K_];
#pragma unroll
  for (int i = 0; i < K_; ++i) tc[i] = Tr[i * K_ + jc];

  if (wv == 1) {
    // ---------------- producer: emissions (r14-proven bits) ----------------
    const int j = lane & 31, h = lane >> 5;
    const int jp = (j < K_) ? j : (K_ - 1);
    float w[64];
    {
      const float4* wp = reinterpret_cast<const float4*>(W + jp * D_ + h * 64);
#pragma unroll
      for (int q = 0; q < 16; ++q) {
        float4 v4 = wp[q];
        w[4*q+0] = v4.x; w[4*q+1] = v4.y; w[4*q+2] = v4.z; w[4*q+3] = v4.w;
      }
    }
    const float* xb = X + (size_t)b * (S_ * D_);
    float2 g = *reinterpret_cast<const float2*>(xb + 2 * lane);
    *reinterpret_cast<float2*>(&ring[0][2 * lane]) = g;
    g = *reinterpret_cast<const float2*>(xb + D_ + 2 * lane);
    asm volatile("" ::: "memory");

    for (int r = 0; r < S_; ++r) {
      const int cur = r & 1;
      float a0 = 0.f, a1 = 0.f, a2 = 0.f, a3 = 0.f;
      const float4* rp = reinterpret_cast<const float4*>(&ring[cur][h * 64]);
#pragma unroll
      for (int q = 0; q < 16; ++q) {
        float4 x4 = rp[q];
        a0 = fmaf(x4.x, w[4*q+0], a0);
        a1 = fmaf(x4.y, w[4*q+1], a1);
        a2 = fmaf(x4.z, w[4*q+2], a2);
        a3 = fmaf(x4.w, w[4*q+3], a3);
      }
      float p = (a0 + a1) + (a2 + a3);
      float e = p + __shfl_xor(p, 32, 64);          // r13/r14-exact bits
      if (r + 1 < S_) *reinterpret_cast<float2*>(&ring[cur ^ 1][2 * lane]) = g;
      if (r + 2 < S_)
        g = *reinterpret_cast<const float2*>(xb + (size_t)(r + 2) * D_ + 2 * lane);
      if (h == 0 && j < K_) e_lds[r * EST + j] = e;
      asm volatile("" ::: "memory");                // data before counter
      if (lane == 0) *(volatile int*)&prog[0] = r + 1;
    }
  } else if (wv == 0) {
    // ---------------- consumer: delta-only serial recurrence ----------------
    v2f tc2[13];
#pragma unroll
    for (int q = 0; q < 13; ++q) tc2[q] = (v2f){tc[2*q], tc[2*q+1]};

    volatile int* vp = &prog[0];
#define WAIT_E(n) do { while (*vp < (n)) {} asm volatile("" ::: "memory"); } while (0)

    WAIT_E(2);
    // row 0 already holds delta_0 = e[0]; gather it
    float4 raw[7];
    {
      const float4* p = reinterpret_cast<const float4*>(&e_lds[0]);
#pragma unroll
      for (int q = 0; q < 7; ++q) raw[q] = p[q];
    }
    float ev_cur = e_lds[EST + jc];                 // e[1][jc]

    for (int ch = 0; ch < 16; ++ch) {
      const int t0 = 16 * ch, tend = t0 + 16;
      const int need = (tend + 1 < S_) ? (tend + 1) : S_;
      WAIT_E(need);
      for (int t = (ch == 0 ? 1 : t0); t < tend; ++t) {
        const v2f* rp2 = reinterpret_cast<const v2f*>(raw);
        v2f v0 = rp2[0] + tc2[0],  v1 = rp2[1] + tc2[1],  v2 = rp2[2] + tc2[2];
        v2f v3 = rp2[3] + tc2[3],  v4 = rp2[4] + tc2[4],  v5 = rp2[5] + tc2[5];
        v2f v6 = rp2[6] + tc2[6],  v7 = rp2[7] + tc2[7],  v8 = rp2[8] + tc2[8];
        v2f v9 = rp2[9] + tc2[9],  va = rp2[10] + tc2[10], vb = rp2[11] + tc2[11];
        v2f vc = rp2[12] + tc2[12];
        v2f a0 = EMAX(v0, v1), a1 = EMAX(v2, v3), a2 = EMAX(v4, v5);
        v2f a3 = EMAX(v6, v7), a4 = EMAX(v8, v9), a5 = EMAX(va, vb);
        v2f b0 = EMAX(a0, a1), b1 = EMAX(a2, a3), b2 = EMAX(a4, a5);
        v2f c0 = EMAX(b0, b1), c1 = EMAX(b2, vc);
        v2f z  = EMAX(c0, c1);
        float best  = fmaxf(z.x, z.y);
        float delta = best + ev_cur;                // same op order as reference

        // publish delta_t over row t; fence; gather row t (r11-proven pattern)
        if (lane < K_) e_lds[t * EST + lane] = delta;
        asm volatile("" ::: "memory");
        {
          const float4* p = reinterpret_cast<const float4*>(&e_lds[t * EST]);
#pragma unroll
          for (int q = 0; q < 7; ++q) raw[q] = p[q];
        }
        int tn = (t + 1 < S_) ? (t + 1) : (S_ - 1);
        ev_cur = e_lds[tn * EST + jc];              // e[t+1] (not yet overwritten)
      }
    }
#undef WAIT_E
    // raw holds delta_255; find 'last' then flag serial-done
    {
      const float* vf = reinterpret_cast<const float*>(raw);
      float bf = vf[0];
#pragma unroll
      for (int i = 1; i < K_; ++i) bf = fmaxf(bf, vf[i]);
      int iA = 63;
#pragma unroll
      for (int i = K_ - 1; i >= 0; --i) iA = (vf[i] == bf) ? i : iA;
      prog[5] = iA;                                 // stash 'last' for later
    }
    asm volatile("" ::: "memory");                  // history+last before flag
    if (lane == 0) *(volatile int*)&prog[1] = 1;
  } else {
    // ---------------- helpers: sleep until serial done ----------------
    while (*(volatile int*)&prog[1] == 0) __builtin_amdgcn_s_sleep(16);
    asm volatile("" ::: "memory");
  }

  if (wv == 1) {                                    // producer also waits
    while (*(volatile int*)&prog[1] == 0) __builtin_amdgcn_s_sleep(16);
    asm volatile("" ::: "memory");
  }

  // ---------------- parallel bp recompute: t == wv (mod 4) ----------------
  for (int t = 1 + wv; t < S_; t += 4) {
    float4 d4[7];
    {
      const float4* dp = reinterpret_cast<const float4*>(&e_lds[(t - 1) * EST]);
#pragma unroll
      for (int q = 0; q < 7; ++q) d4[q] = dp[q];    // uniform broadcast reads
    }
    const float* df = reinterpret_cast<const float*>(d4);
    float v[K_];
#pragma unroll
    for (int i = 0; i < K_; ++i) v[i] = df[i] + tc[i];   // consumer-identical bits
    float m[9];
#pragma unroll
    for (int i = 0; i < 8; ++i) m[i] = fmaxf(fmaxf(v[3*i], v[3*i+1]), v[3*i+2]);
    m[8] = fmaxf(v[24], v[25]);
    float best = fmaxf(fmaxf(fmaxf(m[0], m[1]), m[2]),
                 fmaxf(fmaxf(m[3], m[4]), m[5]));
    best = fmaxf(best, fmaxf(fmaxf(m[6], m[7]), m[8]));
    int idx = 63;
#pragma unroll
    for (int i = K_ - 1; i >= 0; --i) idx = (v[i] == best) ? i : idx;  // first-max
    if (lane < K_) bp[lane][t] = (unsigned char)idx;
  }
  asm volatile("" ::: "memory");
  if (wv != 0) {
    if (lane == 0) *(volatile int*)&prog[2 + wv - 1] = 1;   // prog[2],[3],[4]
    return;                                         // helpers + producer exit
  }

  // consumer waits for all helper bp shares
  while (*(volatile int*)&prog[2] == 0 || *(volatile int*)&prog[3] == 0 ||
         *(volatile int*)&prog[4] == 0) {}
  asm volatile("s_waitcnt lgkmcnt(0)" ::: "memory");

  const int last = prog[5];

  // ---------------- backtrack (r12/r14-proven, fence-only) ----------------
  unsigned char (*spec)[132] = reinterpret_cast<unsigned char (*)[132]>(e_lds);
  int* path_s = reinterpret_cast<int*>(reinterpret_cast<char*>(e_lds) + 4096);

  {
    int c = (lane < K_) ? lane : last;
    for (int k = 0; k < 128; ++k) {
      int t = (lane < K_) ? (128 - k) : (255 - k);
      bool act = (lane < K_) || (lane == 63 && k <= 126);
      if (act) {
        c = bp[c][t];
        if (lane < K_) spec[lane][t - 1] = (unsigned char)c;
        else if (t >= 129) path_s[t - 1] = c;       // covers 128..254
      }
    }
  }
  asm volatile("s_waitcnt lgkmcnt(0)" ::: "memory");

  {
    int sstar = path_s[128];
#pragma unroll
    for (int q2 = 0; q2 < 2; ++q2) {
      int t = q2 * 64 + lane;
      path_s[t] = (int)spec[sstar][t];
    }
    if (lane == 0) path_s[S_ - 1] = last;
  }
  asm volatile("s_waitcnt lgkmcnt(0)" ::: "memory");

  int* o = out + (size_t)b * S_;
#pragma unroll
  for (int q2 = 0; q2 < 4; ++q2) o[q2 * 64 + lane] = path_s[q2 * 64 + lane];
}

extern "C" void kernel_launch(void* const* d_in, const int* in_sizes, int n_in,
                              void* d_out, int out_size, void* d_ws, size_t ws_size,
                              hipStream_t stream) {
  (void)in_sizes; (void)n_in; (void)out_size; (void)d_ws; (void)ws_size;
  const float* X  = (const float*)d_in[0];
  const float* W  = (const float*)d_in[1];
  const float* Tr = (const float*)d_in[2];
  int* outp = (int*)d_out;
  crf_ph<<<B_, 256, 0, stream>>>(X, W, Tr, outp);
}

// Round 17
// 118.434 us; speedup vs baseline: 2.1974x; 2.1974x over previous
//
#include <hip/hip_runtime.h>

#define B_ 1024
#define S_ 256
#define D_ 128
#define K_ 26
#define EST 27   // e_lds row stride (odd -> conflict-free)

// Producer/consumer fused CRF (r14 structure) + 4-segment backtrack:
// Wave 1 (producer): 256 emission rows -> e_lds (r13-proven bits), then
//   sleep-polls serial-done and runs backtrack segments B (128->65) and
//   A (64->1) in disjoint lane groups.
// Wave 0 (consumer): r11-proven minimal recurrence + in-loop bp (r14),
//   then real chain (255->193) + segment C walkers (192->129), stitch, store.
__global__ __launch_bounds__(128, 2) void crf_pc(
    const float* __restrict__ X, const float* __restrict__ W,
    const float* __restrict__ Tr, int* __restrict__ out)
{
  __shared__ __align__(16) float e_lds[S_ * EST];   // 27648 B (aliased in phase 3)
  __shared__ __align__(16) float ring[2][D_];       //  1024 B producer dbuf
  __shared__ __align__(16) float pub[28];           //   112 B
  __shared__ unsigned char bp[K_][260];             //  6760 B
  __shared__ int prog[8];                           //    32 B  (~35.6 KB total)

  const int tid  = threadIdx.x;
  const int lane = tid & 63;
  const int b    = blockIdx.x;

  // phase-3 aliases into e_lds (dead after the serial phase)
  unsigned char (*specC)[64] =
      reinterpret_cast<unsigned char (*)[64]>(reinterpret_cast<char*>(e_lds));
  unsigned char (*specB)[64] =
      reinterpret_cast<unsigned char (*)[64]>(reinterpret_cast<char*>(e_lds) + 2048);
  unsigned char (*specA)[64] =
      reinterpret_cast<unsigned char (*)[64]>(reinterpret_cast<char*>(e_lds) + 4096);
  int* path_s = reinterpret_cast<int*>(reinterpret_cast<char*>(e_lds) + 6144);

  if (tid == 0) { prog[0] = 0; prog[1] = 0; prog[2] = 0; }
  __syncthreads();                                  // both waves alive only here

  if (tid >= 64) {
    // ---------------- producer wave ----------------
    const int j  = lane & 31;
    const int h  = lane >> 5;
    const int jc = (j < K_) ? j : (K_ - 1);
    float w[64];                                    // w[d] = W[jc][h*64+d]
    {
      const float4* wp = reinterpret_cast<const float4*>(W + jc * D_ + h * 64);
#pragma unroll
      for (int q = 0; q < 16; ++q) {
        float4 v4 = wp[q];
        w[4*q+0] = v4.x; w[4*q+1] = v4.y; w[4*q+2] = v4.z; w[4*q+3] = v4.w;
      }
    }
    const float* xb = X + (size_t)b * (S_ * D_);
    float2 g = *reinterpret_cast<const float2*>(xb + 2 * lane);
    *reinterpret_cast<float2*>(&ring[0][2 * lane]) = g;
    g = *reinterpret_cast<const float2*>(xb + D_ + 2 * lane);
    asm volatile("" ::: "memory");

    for (int r = 0; r < S_; ++r) {
      const int cur = r & 1;
      float a0 = 0.f, a1 = 0.f, a2 = 0.f, a3 = 0.f;
      const float4* rp = reinterpret_cast<const float4*>(&ring[cur][h * 64]);
#pragma unroll
      for (int q = 0; q < 16; ++q) {
        float4 x4 = rp[q];
        a0 = fmaf(x4.x, w[4*q+0], a0);
        a1 = fmaf(x4.y, w[4*q+1], a1);
        a2 = fmaf(x4.z, w[4*q+2], a2);
        a3 = fmaf(x4.w, w[4*q+3], a3);
      }
      float p = (a0 + a1) + (a2 + a3);
      float e = p + __shfl_xor(p, 32, 64);          // r13/r14-exact emission bits
      if (r + 1 < S_) *reinterpret_cast<float2*>(&ring[cur ^ 1][2 * lane]) = g;
      if (r + 2 < S_)
        g = *reinterpret_cast<const float2*>(xb + (size_t)(r + 2) * D_ + 2 * lane);
      if (h == 0 && j < K_) e_lds[r * EST + j] = e;
      asm volatile("" ::: "memory");                // data before counter
      if (lane == 0) *(volatile int*)&prog[0] = r + 1;
    }

    // wait (sleeping) for serial-done; then backtrack segments B and A
    while (*(volatile int*)&prog[1] == 0) __builtin_amdgcn_s_sleep(8);
    asm volatile("" ::: "memory");

    {
      const int sl   = lane & 31;
      const bool inB = (lane < K_);                 // lanes 0..25: seg B
      const bool inA = (lane >= 32 && sl < K_);     // lanes 32..57: seg A
      int c = sl;                                   // start state = sl
      for (int k = 0; k < 64; ++k) {
        if (inB) {                                  // t = 128..65 -> idx t-1-64
          int t = 128 - k;
          c = bp[c][t];
          specB[sl][t - 1 - 64] = (unsigned char)c;
        } else if (inA) {                           // t = 64..1 -> idx t-1
          int t = 64 - k;
          c = bp[c][t];
          specA[sl][t - 1] = (unsigned char)c;
        }
      }
    }
    asm volatile("s_waitcnt lgkmcnt(0)" ::: "memory");   // data before flag
    if (lane == 0) *(volatile int*)&prog[2] = 1;
    return;
  }

  // ---------------- consumer wave ----------------
  const int jc = (lane < K_) ? lane : (K_ - 1);
  float tc[K_];
#pragma unroll
  for (int i = 0; i < K_; ++i) tc[i] = Tr[i * K_ + jc];

  volatile int* vprog = prog;
#define WAIT_ROWS(n) do { while (*vprog < (n)) {} asm volatile("" ::: "memory"); } while (0)

  WAIT_ROWS(2);
  float delta = e_lds[jc];                          // t = 0
  if (lane < 28) pub[lane] = -3.4e38f;
  if (lane < K_) pub[lane] = delta;
  asm volatile("" ::: "memory");

  float4 raw[7];
  {
    const float4* p = reinterpret_cast<const float4*>(pub);
#pragma unroll
    for (int q = 0; q < 7; ++q) raw[q] = p[q];      // uniform broadcast reads
  }
  float ev_cur = e_lds[EST + jc];                   // e[1][jc]

  for (int ch = 0; ch < 16; ++ch) {
    const int tend = 16 * (ch + 1);
    const int need = (tend + 1 < S_) ? (tend + 1) : S_;
    WAIT_ROWS(need);                                // rows 0..tend ready
    for (int t = (ch == 0 ? 1 : 16 * ch); t < tend; ++t) {
      float v[K_ + 2];
#pragma unroll
      for (int q = 0; q < 7; ++q) {
        v[4*q+0] = raw[q].x; v[4*q+1] = raw[q].y;
        v[4*q+2] = raw[q].z; v[4*q+3] = raw[q].w;
      }
#pragma unroll
      for (int i = 0; i < K_; ++i) v[i] += tc[i];

      float m[9];
#pragma unroll
      for (int i = 0; i < 8; ++i)
        m[i] = fmaxf(fmaxf(v[3*i], v[3*i+1]), v[3*i+2]);
      m[8] = fmaxf(v[24], v[25]);
      float n0 = fmaxf(fmaxf(m[0], m[1]), m[2]);
      float n1 = fmaxf(fmaxf(m[3], m[4]), m[5]);
      float n2 = fmaxf(fmaxf(m[6], m[7]), m[8]);
      float best = fmaxf(fmaxf(n0, n1), n2);

      delta = best + ev_cur;                        // same op order as reference

      if (lane < K_) pub[lane] = delta;             // publish; fence; gather
      asm volatile("" ::: "memory");
      {
        const float4* p = reinterpret_cast<const float4*>(pub);
#pragma unroll
        for (int q = 0; q < 7; ++q) raw[q] = p[q];
      }

      int tn = (t + 1 < S_) ? (t + 1) : (S_ - 1);
      ev_cur = e_lds[tn * EST + jc];

      int idx = 63;                                 // first-max (jnp.argmax ties)
#pragma unroll
      for (int i = K_ - 1; i >= 0; --i) idx = (v[i] == best) ? i : idx;
      if (lane < K_) bp[lane][t] = (unsigned char)idx;
    }
  }

  // final first-argmax over delta(255)
  int last;
  {
    float v[K_];
#pragma unroll
    for (int q = 0; q < 7; ++q) {
      if (4*q+0 < K_) v[4*q+0] = raw[q].x;
      if (4*q+1 < K_) v[4*q+1] = raw[q].y;
      if (4*q+2 < K_) v[4*q+2] = raw[q].z;
      if (4*q+3 < K_) v[4*q+3] = raw[q].w;
    }
    float bf = v[0];
#pragma unroll
    for (int i = 1; i < K_; ++i) bf = fmaxf(bf, v[i]);
    int iA = 63;
#pragma unroll
    for (int i = K_ - 1; i >= 0; --i) iA = (v[i] == bf) ? i : iA;
    last = iA;
  }

  asm volatile("s_waitcnt lgkmcnt(0)" ::: "memory");   // bp writes drained
  if (lane == 0) *(volatile int*)&prog[1] = 1;         // release producer walkers

  // real chain (lane 63): t=255..193 -> path_s[192..254];
  // segment C walkers (lanes 0..25): t=192..129 -> specC[s][t-1-128]
  {
    const bool isC = (lane < K_);
    const bool isR = (lane == 63);
    int c = isC ? lane : last;
    for (int k = 0; k < 64; ++k) {
      if (isC) {
        int t = 192 - k;
        c = bp[c][t];
        specC[lane][t - 1 - 128] = (unsigned char)c;
      } else if (isR && k <= 62) {
        int t = 255 - k;
        c = bp[c][t];
        path_s[t - 1] = c;                          // covers 192..254
      }
    }
  }
  asm volatile("s_waitcnt lgkmcnt(0)" ::: "memory");

  // wait for producer's segments B and A
  while (*(volatile int*)&prog[2] == 0) {}
  asm volatile("" ::: "memory");

  // stitch: sC = state@192 -> sB = state@128 -> sA = state@64
  {
    int sC = path_s[192];
    int sB = (int)specC[sC][0];
    int sA = (int)specB[sB][0];
    path_s[128 + lane] = (int)specC[sC][lane];
    path_s[64 + lane]  = (int)specB[sB][lane];
    path_s[lane]       = (int)specA[sA][lane];
    if (lane == 0) path_s[S_ - 1] = last;
  }
  asm volatile("s_waitcnt lgkmcnt(0)" ::: "memory");

  int* o = out + (size_t)b * S_;
#pragma unroll
  for (int q2 = 0; q2 < 4; ++q2) o[q2 * 64 + lane] = path_s[q2 * 64 + lane];
#undef WAIT_ROWS
}

extern "C" void kernel_launch(void* const* d_in, const int* in_sizes, int n_in,
                              void* d_out, int out_size, void* d_ws, size_t ws_size,
                              hipStream_t stream) {
  (void)in_sizes; (void)n_in; (void)out_size; (void)d_ws; (void)ws_size;
  const float* X  = (const float*)d_in[0];
  const float* W  = (const float*)d_in[1];
  const float* Tr = (const float*)d_in[2];
  int* outp = (int*)d_out;
  crf_pc<<<B_, 128, 0, stream>>>(X, W, Tr, outp);
}

// Round 18
// 117.566 us; speedup vs baseline: 2.2136x; 1.0074x over previous
//
#include <hip/hip_runtime.h>

#define B_ 1024
#define S_ 256
#define D_ 128
#define K_ 26
#define EST 27   // e_lds row stride (odd -> conflict-free)

// Producer/consumer fused CRF (r17 structure), polish round:
//  - bp packed 4 bytes/word -> 1 ds_write per 4 steps (bpW[K][65] ints)
//  - spec segment stride 68 (odd word stride -> conflict-free walker writes)
//  - consumer wave runs at s_setprio(1)
__global__ __launch_bounds__(128, 2) void crf_pc(
    const float* __restrict__ X, const float* __restrict__ W,
    const float* __restrict__ Tr, int* __restrict__ out)
{
  __shared__ __align__(16) float e_lds[S_ * EST];   // 27648 B (aliased in phase 3)
  __shared__ __align__(16) float ring[2][D_];       //  1024 B producer dbuf
  __shared__ __align__(16) float pub[28];           //   112 B
  __shared__ int bpW[K_][65];                       //  6760 B packed backptrs
  __shared__ int prog[8];                           //    32 B  (~35.6 KB total)

  const int tid  = threadIdx.x;
  const int lane = tid & 63;
  const int b    = blockIdx.x;

  // phase-3 aliases into e_lds (dead after the serial phase); stride 68 bytes
  unsigned char (*specC)[68] =
      reinterpret_cast<unsigned char (*)[68]>(reinterpret_cast<char*>(e_lds));
  unsigned char (*specB)[68] =
      reinterpret_cast<unsigned char (*)[68]>(reinterpret_cast<char*>(e_lds) + 2048);
  unsigned char (*specA)[68] =
      reinterpret_cast<unsigned char (*)[68]>(reinterpret_cast<char*>(e_lds) + 4096);
  int* path_s = reinterpret_cast<int*>(reinterpret_cast<char*>(e_lds) + 6144);

#define BPRD(c, t) ((bpW[(c)][(t) >> 2] >> (((t) & 3) * 8)) & 0xff)

  if (tid == 0) { prog[0] = 0; prog[1] = 0; prog[2] = 0; }
  __syncthreads();                                  // both waves alive only here

  if (tid >= 64) {
    // ---------------- producer wave ----------------
    const int j  = lane & 31;
    const int h  = lane >> 5;
    const int jc = (j < K_) ? j : (K_ - 1);
    float w[64];                                    // w[d] = W[jc][h*64+d]
    {
      const float4* wp = reinterpret_cast<const float4*>(W + jc * D_ + h * 64);
#pragma unroll
      for (int q = 0; q < 16; ++q) {
        float4 v4 = wp[q];
        w[4*q+0] = v4.x; w[4*q+1] = v4.y; w[4*q+2] = v4.z; w[4*q+3] = v4.w;
      }
    }
    const float* xb = X + (size_t)b * (S_ * D_);
    float2 g = *reinterpret_cast<const float2*>(xb + 2 * lane);
    *reinterpret_cast<float2*>(&ring[0][2 * lane]) = g;
    g = *reinterpret_cast<const float2*>(xb + D_ + 2 * lane);
    asm volatile("" ::: "memory");

    for (int r = 0; r < S_; ++r) {
      const int cur = r & 1;
      float a0 = 0.f, a1 = 0.f, a2 = 0.f, a3 = 0.f;
      const float4* rp = reinterpret_cast<const float4*>(&ring[cur][h * 64]);
#pragma unroll
      for (int q = 0; q < 16; ++q) {
        float4 x4 = rp[q];
        a0 = fmaf(x4.x, w[4*q+0], a0);
        a1 = fmaf(x4.y, w[4*q+1], a1);
        a2 = fmaf(x4.z, w[4*q+2], a2);
        a3 = fmaf(x4.w, w[4*q+3], a3);
      }
      float p = (a0 + a1) + (a2 + a3);
      float e = p + __shfl_xor(p, 32, 64);          // r13/r14-exact emission bits
      if (r + 1 < S_) *reinterpret_cast<float2*>(&ring[cur ^ 1][2 * lane]) = g;
      if (r + 2 < S_)
        g = *reinterpret_cast<const float2*>(xb + (size_t)(r + 2) * D_ + 2 * lane);
      if (h == 0 && j < K_) e_lds[r * EST + j] = e;
      asm volatile("" ::: "memory");                // data before counter
      if (lane == 0) *(volatile int*)&prog[0] = r + 1;
    }

    // wait (sleeping) for serial-done; then backtrack segments B and A
    while (*(volatile int*)&prog[1] == 0) __builtin_amdgcn_s_sleep(8);
    asm volatile("" ::: "memory");

    {
      const int sl   = lane & 31;
      const bool inB = (lane < K_);                 // lanes 0..25: seg B
      const bool inA = (lane >= 32 && sl < K_);     // lanes 32..57: seg A
      int c = sl;                                   // start state = sl
      for (int k = 0; k < 64; ++k) {
        if (inB) {                                  // t = 128..65
          int t = 128 - k;
          c = BPRD(c, t);
          specB[sl][t - 1 - 64] = (unsigned char)c;
        } else if (inA) {                           // t = 64..1
          int t = 64 - k;
          c = BPRD(c, t);
          specA[sl][t - 1] = (unsigned char)c;
        }
      }
    }
    asm volatile("s_waitcnt lgkmcnt(0)" ::: "memory");   // data before flag
    if (lane == 0) *(volatile int*)&prog[2] = 1;
    return;
  }

  // ---------------- consumer wave (priority-boosted) ----------------
  __builtin_amdgcn_s_setprio(1);
  const int jc = (lane < K_) ? lane : (K_ - 1);
  float tc[K_];
#pragma unroll
  for (int i = 0; i < K_; ++i) tc[i] = Tr[i * K_ + jc];

  volatile int* vprog = prog;
#define WAIT_ROWS(n) do { while (*vprog < (n)) {} asm volatile("" ::: "memory"); } while (0)

  WAIT_ROWS(2);
  float delta = e_lds[jc];                          // t = 0
  if (lane < 28) pub[lane] = -3.4e38f;
  if (lane < K_) pub[lane] = delta;
  asm volatile("" ::: "memory");

  float4 raw[7];
  {
    const float4* p = reinterpret_cast<const float4*>(pub);
#pragma unroll
    for (int q = 0; q < 7; ++q) raw[q] = p[q];      // uniform broadcast reads
  }
  float ev_cur = e_lds[EST + jc];                   // e[1][jc]
  int bpacc = 0;                                    // packed bp bytes (4 steps)

  for (int ch = 0; ch < 16; ++ch) {
    const int tend = 16 * (ch + 1);
    const int need = (tend + 1 < S_) ? (tend + 1) : S_;
    WAIT_ROWS(need);                                // rows 0..tend ready
    for (int t = (ch == 0 ? 1 : 16 * ch); t < tend; ++t) {
      float v[K_ + 2];
#pragma unroll
      for (int q = 0; q < 7; ++q) {
        v[4*q+0] = raw[q].x; v[4*q+1] = raw[q].y;
        v[4*q+2] = raw[q].z; v[4*q+3] = raw[q].w;
      }
#pragma unroll
      for (int i = 0; i < K_; ++i) v[i] += tc[i];

      float m[9];
#pragma unroll
      for (int i = 0; i < 8; ++i)
        m[i] = fmaxf(fmaxf(v[3*i], v[3*i+1]), v[3*i+2]);
      m[8] = fmaxf(v[24], v[25]);
      float n0 = fmaxf(fmaxf(m[0], m[1]), m[2]);
      float n1 = fmaxf(fmaxf(m[3], m[4]), m[5]);
      float n2 = fmaxf(fmaxf(m[6], m[7]), m[8]);
      float best = fmaxf(fmaxf(n0, n1), n2);

      delta = best + ev_cur;                        // same op order as reference

      if (lane < K_) pub[lane] = delta;             // publish; fence; gather
      asm volatile("" ::: "memory");
      {
        const float4* p = reinterpret_cast<const float4*>(pub);
#pragma unroll
        for (int q = 0; q < 7; ++q) raw[q] = p[q];
      }

      int tn = (t + 1 < S_) ? (t + 1) : (S_ - 1);
      ev_cur = e_lds[tn * EST + jc];

      int idx = 63;                                 // first-max (jnp.argmax ties)
#pragma unroll
      for (int i = K_ - 1; i >= 0; --i) idx = (v[i] == best) ? i : idx;
      bpacc |= idx << ((t & 3) * 8);                // batch 4 bp bytes
      if ((t & 3) == 3) {
        if (lane < K_) bpW[lane][t >> 2] = bpacc;
        bpacc = 0;
      }
    }
  }

  // final first-argmax over delta(255)
  int last;
  {
    float v[K_];
#pragma unroll
    for (int q = 0; q < 7; ++q) {
      if (4*q+0 < K_) v[4*q+0] = raw[q].x;
      if (4*q+1 < K_) v[4*q+1] = raw[q].y;
      if (4*q+2 < K_) v[4*q+2] = raw[q].z;
      if (4*q+3 < K_) v[4*q+3] = raw[q].w;
    }
    float bf = v[0];
#pragma unroll
    for (int i = 1; i < K_; ++i) bf = fmaxf(bf, v[i]);
    int iA = 63;
#pragma unroll
    for (int i = K_ - 1; i >= 0; --i) iA = (v[i] == bf) ? i : iA;
    last = iA;
  }

  asm volatile("s_waitcnt lgkmcnt(0)" ::: "memory");   // bp writes drained
  if (lane == 0) *(volatile int*)&prog[1] = 1;         // release producer walkers

  // real chain (lane 63): t=255..193 -> path_s[192..254];
  // segment C walkers (lanes 0..25): t=192..129 -> specC[s][t-129]
  {
    const bool isC = (lane < K_);
    const bool isR = (lane == 63);
    int c = isC ? lane : last;
    for (int k = 0; k < 64; ++k) {
      if (isC) {
        int t = 192 - k;
        c = BPRD(c, t);
        specC[lane][t - 1 - 128] = (unsigned char)c;
      } else if (isR && k <= 62) {
        int t = 255 - k;
        c = BPRD(c, t);
        path_s[t - 1] = c;                          // covers 192..254
      }
    }
  }
  asm volatile("s_waitcnt lgkmcnt(0)" ::: "memory");

  // wait for producer's segments B and A
  while (*(volatile int*)&prog[2] == 0) {}
  asm volatile("" ::: "memory");

  // stitch: sC = state@192 -> sB = state@128 -> sA = state@64
  {
    int sC = path_s[192];
    int sB = (int)specC[sC][0];
    int sA = (int)specB[sB][0];
    path_s[128 + lane] = (int)specC[sC][lane];
    path_s[64 + lane]  = (int)specB[sB][lane];
    path_s[lane]       = (int)specA[sA][lane];
    if (lane == 0) path_s[S_ - 1] = last;
  }
  asm volatile("s_waitcnt lgkmcnt(0)" ::: "memory");

  int* o = out + (size_t)b * S_;
#pragma unroll
  for (int q2 = 0; q2 < 4; ++q2) o[q2 * 64 + lane] = path_s[q2 * 64 + lane];
#undef WAIT_ROWS
#undef BPRD
}

extern "C" void kernel_launch(void* const* d_in, const int* in_sizes, int n_in,
                              void* d_out, int out_size, void* d_ws, size_t ws_size,
                              hipStream_t stream) {
  (void)in_sizes; (void)n_in; (void)out_size; (void)d_ws; (void)ws_size;
  const float* X  = (const float*)d_in[0];
  const float* W  = (const float*)d_in[1];
  const float* Tr = (const float*)d_in[2];
  int* outp = (int*)d_out;
  crf_pc<<<B_, 128, 0, stream>>>(X, W, Tr, outp);
}